// Round 5
// baseline (435.323 us; speedup 1.0000x reference)
//
#include <hip/hip_runtime.h>

typedef unsigned short u16;
typedef __attribute__((ext_vector_type(8))) short bf16x8;
typedef __attribute__((ext_vector_type(4))) float f32x4;

// ---- constants: B=8 N=4096 C=768 H=8 D=96, M = B*N = 32768 ----
#define M_TOT 32768

__device__ __forceinline__ u16 f2b(float x) {
    union { float f; unsigned u; } c; c.f = x;
    unsigned r = c.u + 0x7fffu + ((c.u >> 16) & 1u);  // RNE
    return (u16)(r >> 16);
}

// ============================================================
// prep_b1: B1[d,k] (96 x 1536 bf16), k<768 -> w1 * sum_h W_qkv_rgb[1536+h*96+d, k]
//                                    k>=768 -> w0 * sum_h W_qkv_depth[768+h*96+d, k-768]
// fb[d] = w1 * sum_h b_qkv_rgb[1536+h*96+d] + w0 * sum_h b_qkv_depth[768+h*96+d]
// ============================================================
__global__ void prep_b1(const float* __restrict__ Wr, const float* __restrict__ Wd,
                        const float* __restrict__ br, const float* __restrict__ bd,
                        const float* __restrict__ aw,
                        u16* __restrict__ B1, float* __restrict__ fb) {
    int id = blockIdx.x * 256 + threadIdx.x;
    if (id >= 96 * 1536) return;
    int d = id / 1536, k = id - d * 1536;
    float w0 = 1.f / (1.f + __expf(-aw[0]));
    float w1 = 1.f / (1.f + __expf(-aw[1]));
    float s = 0.f, v;
    if (k < 768) {
        for (int h = 0; h < 8; h++) s += Wr[(size_t)(1536 + h * 96 + d) * 768 + k];
        v = w1 * s;
    } else {
        for (int h = 0; h < 8; h++) s += Wd[(size_t)(768 + h * 96 + d) * 768 + (k - 768)];
        v = w0 * s;
    }
    B1[id] = f2b(v);
    if (k == 0) {
        float t = 0.f;
        for (int h = 0; h < 8; h++)
            t += w1 * br[1536 + h * 96 + d] + w0 * bd[768 + h * 96 + d];
        fb[d] = t;
    }
}

// ============================================================
// prep_weff: Weff[c,d] (768 x 96 bf16) = sum_h W_out[c, h*96+d]
// ============================================================
__global__ void prep_weff(const float* __restrict__ Wo, u16* __restrict__ Weff) {
    int id = blockIdx.x * 256 + threadIdx.x;
    if (id >= 768 * 96) return;
    int c = id / 96, d = id - c * 96;
    float s = 0.f;
    for (int h = 0; h < 8; h++) s += Wo[(size_t)c * 768 + h * 96 + d];
    Weff[id] = f2b(s);
}

// ============================================================
// gemm_f v6: f(32768 x 96) = [Xr | Xd](32768 x 1536) @ B1^T + fb, bf16 out,
// + fused out0 = x_rgb passthrough.
//
// K-SPLIT-4 structure: grid 2048 blocks x 4 waves; block owns 16 rows.
// Wave w computes a PARTIAL f over K-steps 6w..6w+5:
//   w0: Xr cols   0..383 (+ out0 copy)     w1: Xr cols 384..767 (+ out0 copy)
//   w2: Xd cols   0..383                   w3: Xd cols 384..767
// Main loop: zero barriers, zero inter-wave coupling; per-step depth-1
// register ping-pong (named regs, static indices). A-frags loaded DIRECT from
// global (fragment pattern = dense 16B/lane); B-frags direct from L2-resident
// B1 (294 KB). All s_waitcnt are compiler-generated -> cannot hang.
// End: one __syncthreads + 4-buffer LDS reduce (24 KB), linear indexing
// (addr = m0*96 + e), all 256 threads sum + bias + f2b -> fbuf.
//
// 2048 blocks -> 16 waves/CU resident (VGPR<=128 via launch_bounds(256,4)),
// 2x the old wave count, 4x independent memory streams, no phase round-trips.
// Numerics: each partial keeps the old per-step MFMA order; only the final
// (w0+w1)+w2)+w3 fp32 reassociation differs (<< bf16 input rounding).
// ============================================================
__global__ __launch_bounds__(256, 4) void gemm_f(const float* __restrict__ Xr,
                                                 const float* __restrict__ Xd,
                                                 const u16* __restrict__ B1,
                                                 const float* __restrict__ fb,
                                                 float* __restrict__ out0,
                                                 u16* __restrict__ fbuf) {
    __shared__ float red[4][16 * 96];            // 24 KB partial buffers
    const int tid = threadIdx.x;
    const int lane = tid & 63, wave = tid >> 6;
    const int m0 = blockIdx.x * 16;
    const int fr = lane & 15, fk = (lane >> 4) * 8;   // fragment row / k-offset

    const bool isR = (wave < 2);
    const int base = wave * 6;                        // global K-step base
    const int kx = isR ? base * 64 : base * 64 - 768; // col base within source
    const float* __restrict__ X = isR ? Xr : Xd;

    const float* __restrict__ pa = X + (size_t)(m0 + fr) * 768 + kx + fk;
    float* __restrict__ po = out0 + (size_t)(m0 + fr) * 768 + base * 64 + fk;
    const u16* __restrict__ pb = B1 + fr * 1536 + base * 64 + fk;

    f32x4 acc[6] = {};

    // depth-1 ping-pong: named register sets, all indices compile-time
    float4 c0 = *(const float4*)(pa);
    float4 c1 = *(const float4*)(pa + 4);
    float4 c2 = *(const float4*)(pa + 32);
    float4 c3 = *(const float4*)(pa + 36);

#pragma unroll
    for (int i = 0; i < 6; i++) {
        float4 n0, n1, n2, n3;
        if (i < 5) {
            const float* pn = pa + (i + 1) * 64;
            n0 = *(const float4*)(pn);
            n1 = *(const float4*)(pn + 4);
            n2 = *(const float4*)(pn + 32);
            n3 = *(const float4*)(pn + 36);
        }

        // fused x_rgb passthrough (waves 0,1 cover all cols of all rows once)
        if (isR) {
            float* ps = po + i * 64;
            *(float4*)(ps)      = c0;
            *(float4*)(ps + 4)  = c1;
            *(float4*)(ps + 32) = c2;
            *(float4*)(ps + 36) = c3;
        }

        // B fragments direct from L2 (rows j*16+fr, cols = this wave's k)
        const u16* pbk = pb + i * 64;
        bf16x8 b0[6], b1[6];
#pragma unroll
        for (int j = 0; j < 6; j++) {
            b0[j] = *(const bf16x8*)(pbk + j * 24576);
            b1[j] = *(const bf16x8*)(pbk + j * 24576 + 32);
        }

        // convert fp32 -> bf16 fragments
        bf16x8 ab0, ab1;
        ab0[0] = (short)f2b(c0.x); ab0[1] = (short)f2b(c0.y);
        ab0[2] = (short)f2b(c0.z); ab0[3] = (short)f2b(c0.w);
        ab0[4] = (short)f2b(c1.x); ab0[5] = (short)f2b(c1.y);
        ab0[6] = (short)f2b(c1.z); ab0[7] = (short)f2b(c1.w);
        ab1[0] = (short)f2b(c2.x); ab1[1] = (short)f2b(c2.y);
        ab1[2] = (short)f2b(c2.z); ab1[3] = (short)f2b(c2.w);
        ab1[4] = (short)f2b(c3.x); ab1[5] = (short)f2b(c3.y);
        ab1[6] = (short)f2b(c3.z); ab1[7] = (short)f2b(c3.w);

        // MFMA (per-step order identical to prior passing kernels)
#pragma unroll
        for (int j = 0; j < 6; j++)
            acc[j] = __builtin_amdgcn_mfma_f32_16x16x32_bf16(ab0, b0[j], acc[j], 0, 0, 0);
#pragma unroll
        for (int j = 0; j < 6; j++)
            acc[j] = __builtin_amdgcn_mfma_f32_16x16x32_bf16(ab1, b1[j], acc[j], 0, 0, 0);

        c0 = n0; c1 = n1; c2 = n2; c3 = n3;
    }

    // ---- write partials: C/D layout row=(lane>>4)*4+r, col=j*16+(lane&15) ----
    const int em = (lane >> 4) * 4, en = lane & 15;
#pragma unroll
    for (int j = 0; j < 6; j++)
#pragma unroll
        for (int r = 0; r < 4; r++)
            red[wave][(em + r) * 96 + j * 16 + en] = acc[j][r];

    __syncthreads();

    // ---- reduce: thread handles e = q*256 + tid (linear, conflict-free) ----
#pragma unroll
    for (int q = 0; q < 6; q++) {
        const int e = q * 256 + tid;                  // 0..1535 = row*96+col
        const int col = e % 96;
        float v = ((red[0][e] + red[1][e]) + red[2][e]) + red[3][e] + fb[col];
        fbuf[(size_t)m0 * 96 + e] = f2b(v);
    }
}

// ============================================================
// gemm_o v2 (proven): out1(32768 x 768) = fbuf @ Weff^T + b_out (fp32).
// LDS-free, barrier-free, 16384 waves. fbuf is bf16 in exact A-fragment
// layout -> direct 16B loads. Weff (147 KB) is L2-resident.
// ============================================================
__global__ __launch_bounds__(256) void gemm_o(const u16* __restrict__ fbuf,
                                              const u16* __restrict__ Weff,
                                              const float* __restrict__ bout,
                                              float* __restrict__ out1) {
    const int tid = threadIdx.x;
    const int lane = tid & 63;
    const int wv = (blockIdx.x << 2) | (tid >> 6);      // 0..16383
    const int mg = wv >> 3;                             // row-group 0..2047
    const int nc = (wv & 7) * 96;                       // col-chunk base
    const int fr = lane & 15, fk = (lane >> 4) << 3;

    const u16* pa = fbuf + (size_t)((mg << 4) | fr) * 96 + fk;
    bf16x8 A0 = *(const bf16x8*)(pa);
    bf16x8 A1 = *(const bf16x8*)(pa + 32);
    bf16x8 A2 = *(const bf16x8*)(pa + 64);

    const u16* pb = Weff + (size_t)(nc + fr) * 96 + fk;
    f32x4 acc[6] = {};
#pragma unroll
    for (int j = 0; j < 6; j++) {
        const u16* pbj = pb + j * 1536;                 // 16 rows x 96
        acc[j] = __builtin_amdgcn_mfma_f32_16x16x32_bf16(
            A0, *(const bf16x8*)(pbj), acc[j], 0, 0, 0);
        acc[j] = __builtin_amdgcn_mfma_f32_16x16x32_bf16(
            A1, *(const bf16x8*)(pbj + 32), acc[j], 0, 0, 0);
        acc[j] = __builtin_amdgcn_mfma_f32_16x16x32_bf16(
            A2, *(const bf16x8*)(pbj + 64), acc[j], 0, 0, 0);
    }

    const int em = (lane >> 4) << 2, en = lane & 15;
    const int orow = (mg << 4) + em;
#pragma unroll
    for (int j = 0; j < 6; j++) {
        const int col = nc + j * 16 + en;
        const float bias = bout[col];
#pragma unroll
        for (int r = 0; r < 4; r++)
            out1[(size_t)(orow + r) * 768 + col] = acc[j][r] + bias;
    }
}

// ============================================================
extern "C" void kernel_launch(void* const* d_in, const int* in_sizes, int n_in,
                              void* d_out, int out_size, void* d_ws, size_t ws_size,
                              hipStream_t stream) {
    const float* x_rgb       = (const float*)d_in[0];
    const float* x_depth     = (const float*)d_in[1];
    const float* W_qkv_rgb   = (const float*)d_in[2];
    const float* b_qkv_rgb   = (const float*)d_in[3];
    const float* W_qkv_depth = (const float*)d_in[4];
    const float* b_qkv_depth = (const float*)d_in[5];
    const float* W_out       = (const float*)d_in[6];
    const float* b_out       = (const float*)d_in[7];
    const float* aw          = (const float*)d_in[8];

    float* out0 = (float*)d_out;                      // x_rgb passthrough
    float* out1 = out0 + (size_t)M_TOT * 768;         // x_fusion

    // workspace layout (all 16B-aligned offsets); total ~6.8 MB
    char* w = (char*)d_ws;
    u16*   B1   = (u16*)w;                              // 96*1536*2   = 294912
    float* fb   = (float*)(w + 294912);                 // 96*4 (+pad) -> next at +512
    u16*   Weff = (u16*)(w + 294912 + 512);             // 768*96*2    = 147456
    u16*   fbuf = (u16*)(w + 294912 + 512 + 147456);    // 32768*96*2  = 6291456

    prep_b1<<<576, 256, 0, stream>>>(W_qkv_rgb, W_qkv_depth, b_qkv_rgb, b_qkv_depth,
                                     aw, B1, fb);
    prep_weff<<<288, 256, 0, stream>>>(W_out, Weff);
    gemm_f<<<2048, 256, 0, stream>>>(x_rgb, x_depth, B1, fb, out0, fbuf);
    gemm_o<<<4096, 256, 0, stream>>>(fbuf, Weff, b_out, out1);
}

// Round 6
// 424.876 us; speedup vs baseline: 1.0246x; 1.0246x over previous
//
#include <hip/hip_runtime.h>

typedef unsigned short u16;
typedef __attribute__((ext_vector_type(8))) short bf16x8;
typedef __attribute__((ext_vector_type(4))) float f32x4;

// ---- constants: B=8 N=4096 C=768 H=8 D=96, M = B*N = 32768 ----
#define M_TOT 32768

__device__ __forceinline__ u16 f2b(float x) {
    union { float f; unsigned u; } c; c.f = x;
    unsigned r = c.u + 0x7fffu + ((c.u >> 16) & 1u);  // RNE
    return (u16)(r >> 16);
}

// raw barrier (NO implicit vmcnt drain, unlike __syncthreads) + sched pins
#define BAR() do { __builtin_amdgcn_sched_barrier(0); \
                   __builtin_amdgcn_s_barrier(); \
                   __builtin_amdgcn_sched_barrier(0); } while (0)
// ds-op visibility drain before a barrier following ds_writes
#define LGKM0() asm volatile("s_waitcnt lgkmcnt(0)" ::: "memory")

// ============================================================
// prep (fused): blocks 0..575 -> B1/fb, blocks 576..863 -> Weff.
// B1[d,k] (96 x 1536 bf16): k<768 -> w1 * sum_h W_qkv_rgb[1536+h*96+d, k]
//                           k>=768 -> w0 * sum_h W_qkv_depth[768+h*96+d, k-768]
// fb[d] = w1 * sum_h b_qkv_rgb[1536+h*96+d] + w0 * sum_h b_qkv_depth[768+h*96+d]
// Weff[c,d] (768 x 96 bf16) = sum_h W_out[c, h*96+d]
// ============================================================
__global__ void prep(const float* __restrict__ Wr, const float* __restrict__ Wd,
                     const float* __restrict__ br, const float* __restrict__ bd,
                     const float* __restrict__ aw, const float* __restrict__ Wo,
                     u16* __restrict__ B1, float* __restrict__ fb,
                     u16* __restrict__ Weff) {
    if (blockIdx.x < 576) {
        int id = blockIdx.x * 256 + threadIdx.x;
        if (id >= 96 * 1536) return;
        int d = id / 1536, k = id - d * 1536;
        float w0 = 1.f / (1.f + __expf(-aw[0]));
        float w1 = 1.f / (1.f + __expf(-aw[1]));
        float s = 0.f, v;
        if (k < 768) {
            for (int h = 0; h < 8; h++) s += Wr[(size_t)(1536 + h * 96 + d) * 768 + k];
            v = w1 * s;
        } else {
            for (int h = 0; h < 8; h++) s += Wd[(size_t)(768 + h * 96 + d) * 768 + (k - 768)];
            v = w0 * s;
        }
        B1[id] = f2b(v);
        if (k == 0) {
            float t = 0.f;
            for (int h = 0; h < 8; h++)
                t += w1 * br[1536 + h * 96 + d] + w0 * bd[768 + h * 96 + d];
            fb[d] = t;
        }
    } else {
        int id = (blockIdx.x - 576) * 256 + threadIdx.x;
        if (id >= 768 * 96) return;
        int c = id / 96, d = id - c * 96;
        float s = 0.f;
        for (int h = 0; h < 8; h++) s += Wo[(size_t)c * 768 + h * 96 + d];
        Weff[id] = f2b(s);
    }
}

// ============================================================
// gemm_f v8: f(32768 x 96) = [Xr | Xd](32768 x 1536) @ B1^T + fb, bf16 out.
// EXACTLY the R4-proven v5 pipeline (double-buffered LDS, depth-2 register
// prefetch, raw s_barrier + lgkmcnt(0) drains, LDF=72) with the out0
// passthrough stores REMOVED (copy now lives in gemm_oc at stream rate).
// Traffic: ~201 MB logical read (~100 MB HBM after L3) + 6.3 MB write.
// All vmcnt waits compiler-generated; accumulation order bit-identical to R4.
// ============================================================
#define LDF 72

__device__ __forceinline__ void stage_issue(const float* __restrict__ Xr,
                                            const float* __restrict__ Xd,
                                            const u16* __restrict__ B1,
                                            int m0, int tid, int n,
                                            float4 (&aF)[4], uint4 (&bF)[3]) {
    const float* __restrict__ X = (n < 12) ? Xr : Xd;
    const int kx = (n < 12) ? n * 64 : n * 64 - 768;
#pragma unroll
    for (int r = 0; r < 4; r++) {
        int c = tid + 256 * r, row = c >> 4, colc = (c & 15) * 4;
        aF[r] = *(const float4*)&X[(size_t)(m0 + row) * 768 + kx + colc];
    }
#pragma unroll
    for (int r = 0; r < 3; r++) {
        int c = tid + 256 * r, row = c >> 3, colc = (c & 7) * 8;
        bF[r] = *(const uint4*)&B1[(size_t)row * 1536 + n * 64 + colc];
    }
}

__device__ __forceinline__ void stage_commit(int tid,
                                             const float4 (&aF)[4], const uint4 (&bF)[3],
                                             u16* __restrict__ sAb, u16* __restrict__ sBb) {
#pragma unroll
    for (int r = 0; r < 4; r++) {
        int c = tid + 256 * r, row = c >> 4, colc = (c & 15) * 4;
        ushort4 bv;
        bv.x = f2b(aF[r].x); bv.y = f2b(aF[r].y);
        bv.z = f2b(aF[r].z); bv.w = f2b(aF[r].w);
        *(ushort4*)&sAb[row * LDF + colc] = bv;
    }
#pragma unroll
    for (int r = 0; r < 3; r++) {
        int c = tid + 256 * r, row = c >> 3, colc = (c & 7) * 8;
        *(uint4*)&sBb[row * LDF + colc] = bF[r];
    }
}

__device__ __forceinline__ void mfma_tile(const u16* __restrict__ sAb,
                                          const u16* __restrict__ sBb,
                                          int wave, int fr, int fk, f32x4 (&acc)[6]) {
#pragma unroll
    for (int s = 0; s < 2; s++) {
        bf16x8 a = *(const bf16x8*)&sAb[(wave * 16 + fr) * LDF + s * 32 + fk];
#pragma unroll
        for (int j = 0; j < 6; j++) {
            bf16x8 b = *(const bf16x8*)&sBb[(j * 16 + fr) * LDF + s * 32 + fk];
            acc[j] = __builtin_amdgcn_mfma_f32_16x16x32_bf16(a, b, acc[j], 0, 0, 0);
        }
    }
}

__global__ __launch_bounds__(256) void gemm_f(const float* __restrict__ Xr,
                                              const float* __restrict__ Xd,
                                              const u16* __restrict__ B1,
                                              const float* __restrict__ fb,
                                              u16* __restrict__ fbuf) {
    __shared__ u16 sA[2][64 * LDF];
    __shared__ u16 sB[2][96 * LDF];
    const int tid = threadIdx.x;
    const int m0 = blockIdx.x * 64;
    const int lane = tid & 63, wave = tid >> 6;
    const int fr = lane & 15, fk = (lane >> 4) * 8;

    f32x4 acc[6] = {};
    float4 a0[4], a1[4];
    uint4  b0[3], b1[3];

    // ---- prologue: issue tiles 0 and 1; commit tile 0 to buf0 ----
    stage_issue(Xr, Xd, B1, m0, tid, 0, a0, b0);
    stage_issue(Xr, Xd, B1, m0, tid, 1, a1, b1);
    stage_commit(tid, a0, b0, &sA[0][0], &sB[0][0]);
    LGKM0(); BAR();

    for (int t = 0; t < 24; t += 2) {
        // ==== half A: compute tile t (buf0); prefetch t+2; commit t+1 ====
        if (t + 2 < 24) stage_issue(Xr, Xd, B1, m0, tid, t + 2, a0, b0);
        mfma_tile(&sA[0][0], &sB[0][0], wave, fr, fk, acc);
        BAR();                                        // all waves done reading buf0
        stage_commit(tid, a1, b1, &sA[1][0], &sB[1][0]);
        LGKM0(); BAR();                               // buf1 ready

        // ==== half B: compute tile t+1 (buf1); prefetch t+3; commit t+2 ====
        if (t + 3 < 24) stage_issue(Xr, Xd, B1, m0, tid, t + 3, a1, b1);
        mfma_tile(&sA[1][0], &sB[1][0], wave, fr, fk, acc);
        if (t + 2 < 24) {
            BAR();                                    // all waves done reading buf1
            stage_commit(tid, a0, b0, &sA[0][0], &sB[0][0]);
            LGKM0(); BAR();                           // buf0 ready
        }
    }

    // ---- epilogue: +bias, store bf16. C/D: row=(lane>>4)*4+r, col=lane&15 ----
    const int em = (lane >> 4) * 4, en = lane & 15;
#pragma unroll
    for (int j = 0; j < 6; j++) {
        int dcol = j * 16 + en;
        float bias = fb[dcol];
#pragma unroll
        for (int r = 0; r < 4; r++) {
            int row = m0 + wave * 16 + em + r;
            fbuf[(size_t)row * 96 + dcol] = f2b(acc[j][r] + bias);
        }
    }
}

// ============================================================
// gemm_oc: blocks 0..4095  -> out1(32768 x 768) = fbuf @ Weff^T + b_out (fp32)
//          blocks 4096..6143 -> out0 = x_rgb passthrough (bit-exact float4 copy
//          at stream rate; 2048 blocks x 256 thr x 12 float4 = exactly 32768x768)
// gemm_o part proven in R1/R4/R5: LDS-free, barrier-free, direct 16B fragment
// loads from fbuf; Weff (147 KB) L2-resident.
// ============================================================
__global__ __launch_bounds__(256) void gemm_oc(const u16* __restrict__ fbuf,
                                               const u16* __restrict__ Weff,
                                               const float* __restrict__ bout,
                                               const float* __restrict__ Xr,
                                               float* __restrict__ out0,
                                               float* __restrict__ out1) {
    const int tid = threadIdx.x;
    if (blockIdx.x >= 4096) {
        // ---- out0 copy: contiguous float4 per instruction, fire-and-forget ----
        const size_t base = (size_t)(blockIdx.x - 4096) * 256 + tid;   // 0..524287
        const float4* __restrict__ src = (const float4*)Xr;
        float4* __restrict__ dst = (float4*)out0;
#pragma unroll
        for (int q = 0; q < 12; q++)
            dst[base + (size_t)q * 524288] = src[base + (size_t)q * 524288];
        return;
    }

    const int lane = tid & 63;
    const int wv = (blockIdx.x << 2) | (tid >> 6);      // 0..16383
    const int mg = wv >> 3;                             // row-group 0..2047
    const int nc = (wv & 7) * 96;                       // col-chunk base
    const int fr = lane & 15, fk = (lane >> 4) << 3;

    const u16* pa = fbuf + (size_t)((mg << 4) | fr) * 96 + fk;
    bf16x8 A0 = *(const bf16x8*)(pa);
    bf16x8 A1 = *(const bf16x8*)(pa + 32);
    bf16x8 A2 = *(const bf16x8*)(pa + 64);

    const u16* pb = Weff + (size_t)(nc + fr) * 96 + fk;
    f32x4 acc[6] = {};
#pragma unroll
    for (int j = 0; j < 6; j++) {
        const u16* pbj = pb + j * 1536;                 // 16 rows x 96
        acc[j] = __builtin_amdgcn_mfma_f32_16x16x32_bf16(
            A0, *(const bf16x8*)(pbj), acc[j], 0, 0, 0);
        acc[j] = __builtin_amdgcn_mfma_f32_16x16x32_bf16(
            A1, *(const bf16x8*)(pbj + 32), acc[j], 0, 0, 0);
        acc[j] = __builtin_amdgcn_mfma_f32_16x16x32_bf16(
            A2, *(const bf16x8*)(pbj + 64), acc[j], 0, 0, 0);
    }

    const int em = (lane >> 4) << 2, en = lane & 15;
    const int orow = (mg << 4) + em;
#pragma unroll
    for (int j = 0; j < 6; j++) {
        const int col = nc + j * 16 + en;
        const float bias = bout[col];
#pragma unroll
        for (int r = 0; r < 4; r++)
            out1[(size_t)(orow + r) * 768 + col] = acc[j][r] + bias;
    }
}

// ============================================================
extern "C" void kernel_launch(void* const* d_in, const int* in_sizes, int n_in,
                              void* d_out, int out_size, void* d_ws, size_t ws_size,
                              hipStream_t stream) {
    const float* x_rgb       = (const float*)d_in[0];
    const float* x_depth     = (const float*)d_in[1];
    const float* W_qkv_rgb   = (const float*)d_in[2];
    const float* b_qkv_rgb   = (const float*)d_in[3];
    const float* W_qkv_depth = (const float*)d_in[4];
    const float* b_qkv_depth = (const float*)d_in[5];
    const float* W_out       = (const float*)d_in[6];
    const float* b_out       = (const float*)d_in[7];
    const float* aw          = (const float*)d_in[8];

    float* out0 = (float*)d_out;                      // x_rgb passthrough
    float* out1 = out0 + (size_t)M_TOT * 768;         // x_fusion

    // workspace layout (all 16B-aligned offsets); total ~6.8 MB
    char* w = (char*)d_ws;
    u16*   B1   = (u16*)w;                              // 96*1536*2   = 294912
    float* fb   = (float*)(w + 294912);                 // 96*4 (+pad) -> next at +512
    u16*   Weff = (u16*)(w + 294912 + 512);             // 768*96*2    = 147456
    u16*   fbuf = (u16*)(w + 294912 + 512 + 147456);    // 32768*96*2  = 6291456

    prep<<<864, 256, 0, stream>>>(W_qkv_rgb, W_qkv_depth, b_qkv_rgb, b_qkv_depth,
                                  aw, W_out, B1, fb, Weff);
    gemm_f<<<512, 256, 0, stream>>>(x_rgb, x_depth, B1, fb, fbuf);
    gemm_oc<<<6144, 256, 0, stream>>>(fbuf, Weff, b_out, x_rgb, out0, out1);
}

// Round 7
// 403.730 us; speedup vs baseline: 1.0783x; 1.0524x over previous
//
#include <hip/hip_runtime.h>

typedef unsigned short u16;
typedef __attribute__((ext_vector_type(8))) short bf16x8;
typedef __attribute__((ext_vector_type(4))) float f32x4;

// ---- constants: B=8 N=4096 C=768 H=8 D=96, M = B*N = 32768 ----
#define M_TOT 32768

__device__ __forceinline__ u16 f2b(float x) {
    union { float f; unsigned u; } c; c.f = x;
    unsigned r = c.u + 0x7fffu + ((c.u >> 16) & 1u);  // RNE
    return (u16)(r >> 16);
}

// ============================================================
// prep (fused): blocks 0..575 -> B1p/fb, blocks 576..863 -> Weff.
//
// B1p is the fused V-projection matrix stored in FRAGMENT-MAJOR order so each
// gemm_f B-load is one dense coalesced 1KB instruction:
//   B1p[((i*12 + q)*64 + l)*8 + e]  (i=K-step 0..23, q=frag 0..11, l=lane, e=0..7)
//   maps to logical B1[d][k] with  s=q/6, j=q%6,
//   d = j*16 + (l&15),  k = i*64 + s*32 + ((l>>4)<<3) + e.
// Logical B1[d][k]: k<768 -> w1 * sum_h W_qkv_rgb[1536+h*96+d, k]
//                   k>=768 -> w0 * sum_h W_qkv_depth[768+h*96+d, k-768]
// fb[d] = w1 * sum_h b_qkv_rgb[1536+h*96+d] + w0 * sum_h b_qkv_depth[768+h*96+d]
// Weff[c,d] (768 x 96 bf16) = sum_h W_out[c, h*96+d]
// ============================================================
__global__ void prep(const float* __restrict__ Wr, const float* __restrict__ Wd,
                     const float* __restrict__ br, const float* __restrict__ bd,
                     const float* __restrict__ aw, const float* __restrict__ Wo,
                     u16* __restrict__ B1p, float* __restrict__ fb,
                     u16* __restrict__ Weff) {
    if (blockIdx.x < 576) {
        int id = blockIdx.x * 256 + threadIdx.x;      // 0..147455 exactly
        if (id >= 96 * 1536) return;
        const int e = id & 7;
        const int l = (id >> 3) & 63;
        const int g = id >> 9;                        // (i*12+q) 0..287
        const int q = g % 12, i = g / 12;
        const int d = (q % 6) * 16 + (l & 15);
        const int k = i * 64 + (q / 6) * 32 + ((l >> 4) << 3) + e;

        float w0 = 1.f / (1.f + __expf(-aw[0]));
        float w1 = 1.f / (1.f + __expf(-aw[1]));
        float s = 0.f, v;
        if (k < 768) {
            for (int h = 0; h < 8; h++) s += Wr[(size_t)(1536 + h * 96 + d) * 768 + k];
            v = w1 * s;
        } else {
            for (int h = 0; h < 8; h++) s += Wd[(size_t)(768 + h * 96 + d) * 768 + (k - 768)];
            v = w0 * s;
        }
        B1p[id] = f2b(v);
        if (k == 0) {                                 // exactly once per d
            float t = 0.f;
            for (int h = 0; h < 8; h++)
                t += w1 * br[1536 + h * 96 + d] + w0 * bd[768 + h * 96 + d];
            fb[d] = t;
        }
    } else {
        int id = (blockIdx.x - 576) * 256 + threadIdx.x;
        if (id >= 768 * 96) return;
        int c = id / 96, d = id - c * 96;
        float s = 0.f;
        for (int h = 0; h < 8; h++) s += Wo[(size_t)c * 768 + h * 96 + d];
        Weff[id] = f2b(s);
    }
}

// ============================================================
// gemm_f v9: f(32768 x 96) = [Xr | Xd](32768 x 1536) @ B1^T + fb, bf16 out,
// + fused out0 = x_rgb passthrough (bit-exact, from the same registers).
//
// ZERO barriers, ZERO LDS, zero hand-written waits. Each wave owns 16 rows.
// Depth-1 register ping-pong of BOTH operands: iteration i issues A(i+1)
// (4x float4, dense fragment pattern) and B(i+1) (12x dense 1KB loads from
// fragment-major B1p, L2-resident) BEFORE computing step i. The compiler's
// vmcnt wait for step-i data therefore leaves the entire step-(i+1) load set
// (16 ops, ~16KB/wave) in flight -> ~128KB/CU outstanding at 8 waves/CU,
// ~14x what 900cy HBM latency requires: BW-saturated, no FIFO collapse.
// (R1's flaw: B(i) loaded in-iteration -> its wait drained A(i+1). Fixed.)
//
// Fully unrolled (24 steps): all ping-pong indices compile-time (rule #20).
// Accumulation order bit-identical to all passing rounds.
// ============================================================
__global__ __launch_bounds__(256, 2) void gemm_f(const float* __restrict__ Xr,
                                                 const float* __restrict__ Xd,
                                                 const u16* __restrict__ B1p,
                                                 const float* __restrict__ fb,
                                                 float* __restrict__ out0,
                                                 u16* __restrict__ fbuf) {
    const int tid = threadIdx.x;
    const int lane = tid & 63;
    const int wv = (blockIdx.x << 2) | (tid >> 6);    // 0..2047, 16 rows each
    const int fr = lane & 15, fkq = lane >> 4;
    const size_t rowoff = (size_t)((wv << 4) | fr) * 768;

    const float* __restrict__ pr = Xr + rowoff + fkq * 8;
    const float* __restrict__ pd = Xd + rowoff + fkq * 8;
    float* __restrict__ po = out0 + rowoff + fkq * 8;
    const u16* __restrict__ pB = B1p + lane * 8;      // frag-major: +q*512, +i*6144

    f32x4 acc[6] = {};
    float4 A[2][4];
    bf16x8 Bf[2][12];

    // ---- prologue: load step 0 (A + B) ----
    A[0][0] = *(const float4*)(pr);
    A[0][1] = *(const float4*)(pr + 4);
    A[0][2] = *(const float4*)(pr + 32);
    A[0][3] = *(const float4*)(pr + 36);
#pragma unroll
    for (int q = 0; q < 12; q++)
        Bf[0][q] = *(const bf16x8*)(pB + q * 512);

#pragma unroll
    for (int i = 0; i < 24; i++) {
        const int cur = i & 1, nxt = cur ^ 1;

        // ---- prefetch step i+1: A and B together (before any use of step i) ----
        if (i < 23) {
            const int n = i + 1;
            const float* s = (n < 12) ? (pr + n * 64) : (pd + (n - 12) * 64);
            A[nxt][0] = *(const float4*)(s);
            A[nxt][1] = *(const float4*)(s + 4);
            A[nxt][2] = *(const float4*)(s + 32);
            A[nxt][3] = *(const float4*)(s + 36);
            const u16* bb = pB + n * 6144;
#pragma unroll
            for (int q = 0; q < 12; q++)
                Bf[nxt][q] = *(const bf16x8*)(bb + q * 512);
        }

        // ---- fused x_rgb passthrough (steps 0..11 cover every element once) ----
        if (i < 12) {
            float* ps = po + i * 64;
            *(float4*)(ps)      = A[cur][0];
            *(float4*)(ps + 4)  = A[cur][1];
            *(float4*)(ps + 32) = A[cur][2];
            *(float4*)(ps + 36) = A[cur][3];
        }

        // ---- convert fp32 -> bf16 fragments ----
        bf16x8 ab0, ab1;
        ab0[0] = (short)f2b(A[cur][0].x); ab0[1] = (short)f2b(A[cur][0].y);
        ab0[2] = (short)f2b(A[cur][0].z); ab0[3] = (short)f2b(A[cur][0].w);
        ab0[4] = (short)f2b(A[cur][1].x); ab0[5] = (short)f2b(A[cur][1].y);
        ab0[6] = (short)f2b(A[cur][1].z); ab0[7] = (short)f2b(A[cur][1].w);
        ab1[0] = (short)f2b(A[cur][2].x); ab1[1] = (short)f2b(A[cur][2].y);
        ab1[2] = (short)f2b(A[cur][2].z); ab1[3] = (short)f2b(A[cur][2].w);
        ab1[4] = (short)f2b(A[cur][3].x); ab1[5] = (short)f2b(A[cur][3].y);
        ab1[6] = (short)f2b(A[cur][3].z); ab1[7] = (short)f2b(A[cur][3].w);

        // ---- MFMA (bit-identical order: s=0 j=0..5, then s=1 j=0..5) ----
#pragma unroll
        for (int j = 0; j < 6; j++)
            acc[j] = __builtin_amdgcn_mfma_f32_16x16x32_bf16(ab0, Bf[cur][j], acc[j], 0, 0, 0);
#pragma unroll
        for (int j = 0; j < 6; j++)
            acc[j] = __builtin_amdgcn_mfma_f32_16x16x32_bf16(ab1, Bf[cur][6 + j], acc[j], 0, 0, 0);
    }

    // ---- epilogue: +bias, store bf16. C/D: row=(lane>>4)*4+r, col=lane&15 ----
    const int em = (lane >> 4) << 2, en = lane & 15;
    const int orow = (wv << 4) + em;
#pragma unroll
    for (int j = 0; j < 6; j++) {
        const int dcol = j * 16 + en;
        const float bias = fb[dcol];
#pragma unroll
        for (int r = 0; r < 4; r++)
            fbuf[(size_t)(orow + r) * 96 + dcol] = f2b(acc[j][r] + bias);
    }
}

// ============================================================
// gemm_o (proven R1/R4/R5): out1(32768 x 768) = fbuf @ Weff^T + b_out (fp32).
// LDS-free, barrier-free, 16384 waves. fbuf is bf16 in exact A-fragment
// layout -> direct 16B loads. Weff (147 KB) is L2-resident.
// ============================================================
__global__ __launch_bounds__(256) void gemm_o(const u16* __restrict__ fbuf,
                                              const u16* __restrict__ Weff,
                                              const float* __restrict__ bout,
                                              float* __restrict__ out1) {
    const int tid = threadIdx.x;
    const int lane = tid & 63;
    const int wv = (blockIdx.x << 2) | (tid >> 6);      // 0..16383
    const int mg = wv >> 3;                             // row-group 0..2047
    const int nc = (wv & 7) * 96;                       // col-chunk base
    const int fr = lane & 15, fk = (lane >> 4) << 3;

    const u16* pa = fbuf + (size_t)((mg << 4) | fr) * 96 + fk;
    bf16x8 A0 = *(const bf16x8*)(pa);
    bf16x8 A1 = *(const bf16x8*)(pa + 32);
    bf16x8 A2 = *(const bf16x8*)(pa + 64);

    const u16* pb = Weff + (size_t)(nc + fr) * 96 + fk;
    f32x4 acc[6] = {};
#pragma unroll
    for (int j = 0; j < 6; j++) {
        const u16* pbj = pb + j * 1536;                 // 16 rows x 96
        acc[j] = __builtin_amdgcn_mfma_f32_16x16x32_bf16(
            A0, *(const bf16x8*)(pbj), acc[j], 0, 0, 0);
        acc[j] = __builtin_amdgcn_mfma_f32_16x16x32_bf16(
            A1, *(const bf16x8*)(pbj + 32), acc[j], 0, 0, 0);
        acc[j] = __builtin_amdgcn_mfma_f32_16x16x32_bf16(
            A2, *(const bf16x8*)(pbj + 64), acc[j], 0, 0, 0);
    }

    const int em = (lane >> 4) << 2, en = lane & 15;
    const int orow = (mg << 4) + em;
#pragma unroll
    for (int j = 0; j < 6; j++) {
        const int col = nc + j * 16 + en;
        const float bias = bout[col];
#pragma unroll
        for (int r = 0; r < 4; r++)
            out1[(size_t)(orow + r) * 768 + col] = acc[j][r] + bias;
    }
}

// ============================================================
extern "C" void kernel_launch(void* const* d_in, const int* in_sizes, int n_in,
                              void* d_out, int out_size, void* d_ws, size_t ws_size,
                              hipStream_t stream) {
    const float* x_rgb       = (const float*)d_in[0];
    const float* x_depth     = (const float*)d_in[1];
    const float* W_qkv_rgb   = (const float*)d_in[2];
    const float* b_qkv_rgb   = (const float*)d_in[3];
    const float* W_qkv_depth = (const float*)d_in[4];
    const float* b_qkv_depth = (const float*)d_in[5];
    const float* W_out       = (const float*)d_in[6];
    const float* b_out       = (const float*)d_in[7];
    const float* aw          = (const float*)d_in[8];

    float* out0 = (float*)d_out;                      // x_rgb passthrough
    float* out1 = out0 + (size_t)M_TOT * 768;         // x_fusion

    // workspace layout (all 16B-aligned offsets); total ~6.8 MB
    char* w = (char*)d_ws;
    u16*   B1p  = (u16*)w;                              // 96*1536*2   = 294912
    float* fb   = (float*)(w + 294912);                 // 96*4 (+pad) -> next at +512
    u16*   Weff = (u16*)(w + 294912 + 512);             // 768*96*2    = 147456
    u16*   fbuf = (u16*)(w + 294912 + 512 + 147456);    // 32768*96*2  = 6291456

    prep<<<864, 256, 0, stream>>>(W_qkv_rgb, W_qkv_depth, b_qkv_rgb, b_qkv_depth,
                                  aw, W_out, B1p, fb, Weff);
    gemm_f<<<512, 256, 0, stream>>>(x_rgb, x_depth, B1p, fb, out0, fbuf);
    gemm_o<<<4096, 256, 0, stream>>>(fbuf, Weff, b_out, out1);
}